// Round 5
// baseline (322.833 us; speedup 1.0000x reference)
//
#include <hip/hip_runtime.h>
#include <hip/hip_bf16.h>

#define L 4096
#define D 256
#define H 8
#define DH 32

typedef __attribute__((ext_vector_type(8))) short bf16x8;
typedef __attribute__((ext_vector_type(4))) float f32x4;

#define LOG2E 1.4426950408889634f
#define RS (0.17677669529663688f * LOG2E)   // 1/sqrt(DH) * log2(e), folded into Q

__device__ __forceinline__ ushort f2bf(float f) {
    union { float f; unsigned int i; } v; v.f = f;
    unsigned int x = v.i;
    return (ushort)((x + 0x7fffu + ((x >> 16) & 1u)) >> 16);   // RNE
}
__device__ __forceinline__ bf16x8 cvt8(const float* p) {
    float4 a = *(const float4*)p;
    float4 b = *(const float4*)(p + 4);
    bf16x8 r;
    r[0] = (short)f2bf(a.x); r[1] = (short)f2bf(a.y);
    r[2] = (short)f2bf(a.z); r[3] = (short)f2bf(a.w);
    r[4] = (short)f2bf(b.x); r[5] = (short)f2bf(b.y);
    r[6] = (short)f2bf(b.z); r[7] = (short)f2bf(b.w);
    return r;
}

// ---------------- Kernel 0: prepack ----------------
// b<4096: mask row -> permuted u8 stream m8p[row][l15][kt][nt] = (e<<2), coalesced via LDS
// [4096,4608): x->bf16 ; [4608,4704): in_w ; [4704,4736): out_w
__global__ __launch_bounds__(256) void pack_kernel(
        const int* __restrict__ mask, const float* __restrict__ x,
        const float* __restrict__ wi, const float* __restrict__ wo,
        unsigned char* __restrict__ m8p, ushort* __restrict__ xb,
        ushort* __restrict__ wib, ushort* __restrict__ wob)
{
    const int b = blockIdx.x;
    const int tid = threadIdx.x;
    if (b < 4096) {
        __shared__ unsigned char rb[4096];
        const int4* src = (const int4*)(mask + (size_t)b * 4096);
#pragma unroll
        for (int i = 0; i < 4; i++) {
            const int j = i * 256 + tid;           // int4 index: ints 4j..4j+3
            int4 v = src[j];
            ((unsigned int*)rb)[j] =
                ((unsigned int)(v.x << 2) & 0xffu)        |
                (((unsigned int)(v.y << 2) & 0xffu) << 8) |
                (((unsigned int)(v.z << 2) & 0xffu) << 16)|
                (((unsigned int)(v.w << 2) & 0xffu) << 24);
        }
        __syncthreads();
        const int l15 = tid >> 4;
        const int kt0 = (tid & 15) * 4;
        unsigned int ow[4];
#pragma unroll
        for (int j4 = 0; j4 < 4; j4++) {
            const int kt = kt0 + j4;
            ow[j4] = (unsigned int)rb[kt * 64 + l15]
                   | ((unsigned int)rb[kt * 64 + 16 + l15] << 8)
                   | ((unsigned int)rb[kt * 64 + 32 + l15] << 16)
                   | ((unsigned int)rb[kt * 64 + 48 + l15] << 24);
        }
        int4 o; o.x = ow[0]; o.y = ow[1]; o.z = ow[2]; o.w = ow[3];
        ((int4*)(m8p + (size_t)b * 4096))[tid] = o;
    } else if (b < 4608) {
        const int t = (b - 4096) * 256 + tid;
        ((bf16x8*)xb)[t] = cvt8(x + t * 8);
    } else if (b < 4704) {
        const int t = (b - 4608) * 256 + tid;
        ((bf16x8*)wib)[t] = cvt8(wi + t * 8);
    } else {
        const int t = (b - 4704) * 256 + tid;
        ((bf16x8*)wob)[t] = cvt8(wo + t * 8);
    }
}

// ---------------- Kernel 1: QKV projection (bf16 in, bf16 Q/K/V^T out) ----------------
__global__ __launch_bounds__(256) void qkv_kernel(
        const ushort* __restrict__ xb, const ushort* __restrict__ wb,
        const float* __restrict__ b,
        ushort* __restrict__ Qb, ushort* __restrict__ Kb, ushort* __restrict__ Vt)
{
    const int lane = threadIdx.x & 63, wv = threadIdx.x >> 6;
    const int quad = lane >> 4, l15 = lane & 15;
    const int m0 = blockIdx.x * 64 + wv * 16;
    const int n0 = blockIdx.y * 64;

    f32x4 acc[4] = {};
    for (int ks = 0; ks < 8; ks++) {
        const int kd = ks * 32 + quad * 8;
        bf16x8 af = *(const bf16x8*)(xb + (m0 + l15) * D + kd);
#pragma unroll
        for (int nt = 0; nt < 4; nt++) {
            bf16x8 bfr = *(const bf16x8*)(wb + (n0 + nt * 16 + l15) * D + kd);
            acc[nt] = __builtin_amdgcn_mfma_f32_16x16x32_bf16(af, bfr, acc[nt], 0, 0, 0);
        }
    }
#pragma unroll
    for (int nt = 0; nt < 4; nt++) {
        const int j = n0 + nt * 16 + l15;
        const float bias = b[j];
#pragma unroll
        for (int r = 0; r < 4; r++) {
            const int row = m0 + quad * 4 + r;
            const float val = acc[nt][r] + bias;
            if (j < 256) {
                Qb[((j >> 5) * L + row) * DH + (j & 31)] = f2bf(val * RS);
            } else if (j < 512) {
                const int jj = j - 256;
                Kb[((jj >> 5) * L + row) * DH + (jj & 31)] = f2bf(val);
            } else {
                const int jj = j - 512;
                Vt[((jj >> 5) * DH + (jj & 31)) * L + row] = f2bf(val);
            }
        }
    }
}

// ---------------- Kernel 2: K-split flash attention, edge bias, no barriers ----------------
// grid (256 q-tiles, SP splits); 8 waves = 8 heads; ktcount = 64/SP iterations per block.
__global__ __launch_bounds__(512, 6) void attn_kernel(
        const ushort* __restrict__ Qb, const ushort* __restrict__ Kb,
        const ushort* __restrict__ Vt, const unsigned char* __restrict__ m8p,
        const float* __restrict__ edge_bias,
        float* __restrict__ Opart, float* __restrict__ lpart, int ktcount)
{
    __shared__ float ebtab[8 * 16];
    __shared__ __align__(16) ushort Pl[8 * 16 * 72];

    const int tid = threadIdx.x;
    const int lane = tid & 63, h = tid >> 6;
    const int quad = lane >> 4, l15 = lane & 15;
    const int q0 = blockIdx.x * 16;
    const int ktbase = blockIdx.y * ktcount;

    if (lane < 16) {
        ebtab[h * 16 + lane] = (lane < 14)
            ? __builtin_amdgcn_exp2f(edge_bias[lane * H + h] * LOG2E) : 1.0f;
    }
    asm volatile("s_waitcnt lgkmcnt(0)" ::: "memory");   // wave-private table

    const bf16x8 qf = *(const bf16x8*)(Qb + (h * L + q0 + l15) * DH + quad * 8);
    const char* ebh = (const char*)(ebtab + h * 16);
    ushort* Pw = Pl + h * (16 * 72);

    const ushort* Kh  = Kb + h * L * DH;
    const ushort* Vh0 = Vt + (h * DH + l15) * L;
    const ushort* Vh1 = Vt + (h * DH + 16 + l15) * L;

    f32x4 o0 = {}, o1 = {};
    float lrow[4] = {0.f, 0.f, 0.f, 0.f};

    const unsigned char* mb[4];
#pragma unroll
    for (int r = 0; r < 4; r++)
        mb[r] = m8p + ((size_t)(q0 + quad * 4 + r) * 16 + l15) * 256 + ktbase * 4;

    for (int kb = 0; kb < ktcount; kb += 4) {
        int4 mw[4];
#pragma unroll
        for (int r = 0; r < 4; r++) mw[r] = *(const int4*)(mb[r] + kb * 4);

#pragma unroll
        for (int ki = 0; ki < 4; ki++) {
            const int k0 = (ktbase + kb + ki) * 64;

            // S = (RS*Q) K^T  (16x64), log2 domain
            f32x4 sv[4];
#pragma unroll
            for (int nt = 0; nt < 4; nt++) {
                bf16x8 kf = *(const bf16x8*)(Kh + (k0 + nt * 16 + l15) * DH + quad * 8);
                f32x4 z = {};
                sv[nt] = __builtin_amdgcn_mfma_f32_16x16x32_bf16(qf, kf, z, 0, 0, 0);
            }

            // P = exp2(S) * exp(bias[e]); e<<2 pre-baked in mask bytes
#pragma unroll
            for (int nt = 0; nt < 4; nt++) {
#pragma unroll
                for (int r = 0; r < 4; r++) {
                    const unsigned int wvr = (ki == 0) ? (unsigned int)mw[r].x
                                           : (ki == 1) ? (unsigned int)mw[r].y
                                           : (ki == 2) ? (unsigned int)mw[r].z
                                                       : (unsigned int)mw[r].w;
                    const int e4 = (wvr >> (nt * 8)) & 255;
                    const float ebv = *(const float*)(ebh + e4);
                    const float p = __builtin_amdgcn_exp2f(sv[nt][r]) * ebv;
                    lrow[r] += p;
                    union { float f; unsigned int u; } pu; pu.f = p;
                    Pw[(quad * 4 + r) * 72 + nt * 16 + l15] = (ushort)((pu.u + 0x8000u) >> 16);
                }
            }
            asm volatile("s_waitcnt lgkmcnt(0)" ::: "memory");   // wave-private RAW fence

            // O += P V
#pragma unroll
            for (int ks2 = 0; ks2 < 2; ks2++) {
                bf16x8 pf = *(const bf16x8*)(Pw + l15 * 72 + ks2 * 32 + quad * 8);
                bf16x8 v0 = *(const bf16x8*)(Vh0 + k0 + ks2 * 32 + quad * 8);
                bf16x8 v1 = *(const bf16x8*)(Vh1 + k0 + ks2 * 32 + quad * 8);
                o0 = __builtin_amdgcn_mfma_f32_16x16x32_bf16(pf, v0, o0, 0, 0, 0);
                o1 = __builtin_amdgcn_mfma_f32_16x16x32_bf16(pf, v1, o1, 0, 0, 0);
            }
        }
    }

    // reduce row-sums across the 16 lanes sharing each q-row
#pragma unroll
    for (int off = 1; off < 16; off <<= 1) {
#pragma unroll
        for (int r = 0; r < 4; r++)
            lrow[r] += __shfl_xor(lrow[r], off, 64);
    }

    float* Op = Opart + (size_t)(blockIdx.y * 8 + h) * L * 32;
#pragma unroll
    for (int r = 0; r < 4; r++) {
        const int row = q0 + quad * 4 + r;
        Op[row * 32 + l15] = o0[r];
        Op[row * 32 + 16 + l15] = o1[r];
    }
    if (l15 == 0) {
#pragma unroll
        for (int r = 0; r < 4; r++)
            lpart[(size_t)(blockIdx.y * 8 + h) * L + q0 + quad * 4 + r] = lrow[r];
    }
}

// ---------------- Kernel 2b: combine split partials -> AO bf16 ----------------
__global__ __launch_bounds__(256) void finalize_kernel(
        const float* __restrict__ Opart, const float* __restrict__ lpart,
        ushort* __restrict__ AO, int SP)
{
    const int t = blockIdx.x * 256 + threadIdx.x;    // t in [0, L*D)
    const int q = t >> 8, c = t & 255;
    const int h = c >> 5, dh = c & 31;
    float o = 0.f, l = 0.f;
    for (int s = 0; s < SP; s++) {
        o += Opart[((size_t)(s * 8 + h) * L + q) * 32 + dh];
        l += lpart[(size_t)(s * 8 + h) * L + q];
    }
    AO[t] = f2bf(o / l);
}

// ---------------- Kernel 3: output projection (bf16 AO, bf16 W -> fp32 out) ----------------
__global__ __launch_bounds__(256) void oproj_kernel(
        const ushort* __restrict__ AO, const ushort* __restrict__ wb,
        const float* __restrict__ b, float* __restrict__ out)
{
    const int lane = threadIdx.x & 63, wv = threadIdx.x >> 6;
    const int quad = lane >> 4, l15 = lane & 15;
    const int m0 = blockIdx.x * 64 + wv * 16;
    const int n0 = blockIdx.y * 64;

    f32x4 acc[4] = {};
    for (int ks = 0; ks < 8; ks++) {
        const int kd = ks * 32 + quad * 8;
        bf16x8 af = *(const bf16x8*)(AO + (m0 + l15) * D + kd);
#pragma unroll
        for (int nt = 0; nt < 4; nt++) {
            bf16x8 bfr = *(const bf16x8*)(wb + (n0 + nt * 16 + l15) * D + kd);
            acc[nt] = __builtin_amdgcn_mfma_f32_16x16x32_bf16(af, bfr, acc[nt], 0, 0, 0);
        }
    }
#pragma unroll
    for (int nt = 0; nt < 4; nt++) {
        const int j = n0 + nt * 16 + l15;
        const float bias = b[j];
#pragma unroll
        for (int r = 0; r < 4; r++) {
            const int row = m0 + quad * 4 + r;
            out[row * D + j] = acc[nt][r] + bias;
        }
    }
}

extern "C" void kernel_launch(void* const* d_in, const int* in_sizes, int n_in,
                              void* d_out, int out_size, void* d_ws, size_t ws_size,
                              hipStream_t stream) {
    const float* x     = (const float*)d_in[0];
    const int*   mask  = (const int*)d_in[1];
    const float* in_w  = (const float*)d_in[2];
    const float* in_b  = (const float*)d_in[3];
    const float* out_w = (const float*)d_in[4];
    const float* out_b = (const float*)d_in[5];
    const float* eb    = (const float*)d_in[6];

    ushort* ws = (ushort*)d_ws;
    ushort* Qb  = ws;                          // 1M elems each
    ushort* Kb  = Qb + H * L * DH;
    ushort* Vt  = Kb + H * L * DH;
    ushort* xb  = Vt + H * L * DH;             // x bf16; reused as AO after attn
    ushort* wib = xb + L * D;
    ushort* wob = wib + 3 * D * D;
    unsigned char* m8p = (unsigned char*)(wob + D * D);          // 16 MB
    float* Opart = (float*)(m8p + (size_t)L * L);                // SP*16 MB... per split 4 MB*? (8*L*32 fp32 = 4 MB/split... actually 4,194,304 B)
    // sizes: fixed part = 8,912,896 + 16,777,216 = 25,690,112 bytes
    // per split: Opart 4,194,304 + lpart 131,072 bytes
    int SP = (ws_size >= (size_t)25690112 + 4u * 4325376u) ? 4
           : (ws_size >= (size_t)25690112 + 2u * 4325376u) ? 2 : 1;
    float* lpart = Opart + (size_t)SP * H * L * DH;
    ushort* AO = xb;
    float* out = (float*)d_out;

    pack_kernel<<<dim3(4736), 256, 0, stream>>>(mask, x, in_w, out_w, m8p, xb, wib, wob);
    qkv_kernel<<<dim3(64, 12), 256, 0, stream>>>(xb, wib, in_b, Qb, Kb, Vt);
    attn_kernel<<<dim3(256, SP), 512, 0, stream>>>(Qb, Kb, Vt, m8p, eb, Opart, lpart, 64 / SP);
    finalize_kernel<<<dim3(4096), 256, 0, stream>>>(Opart, lpart, AO, SP);
    oproj_kernel<<<dim3(64, 4), 256, 0, stream>>>(AO, wob, out_b, out);
}

// Round 6
// 297.256 us; speedup vs baseline: 1.0860x; 1.0860x over previous
//
#include <hip/hip_runtime.h>
#include <hip/hip_bf16.h>

#define L 4096
#define D 256
#define H 8
#define DH 32

typedef __attribute__((ext_vector_type(8))) short bf16x8;
typedef __attribute__((ext_vector_type(4))) float f32x4;

#define LOG2E 1.4426950408889634f
#define RS (0.17677669529663688f * LOG2E)   // 1/sqrt(DH) * log2(e), folded into Q

__device__ __forceinline__ ushort f2bf(float f) {
    union { float f; unsigned int i; } v; v.f = f;
    unsigned int x = v.i;
    return (ushort)((x + 0x7fffu + ((x >> 16) & 1u)) >> 16);   // RNE
}
__device__ __forceinline__ bf16x8 cvt8(const float* p) {
    float4 a = *(const float4*)p;
    float4 b = *(const float4*)(p + 4);
    bf16x8 r;
    r[0] = (short)f2bf(a.x); r[1] = (short)f2bf(a.y);
    r[2] = (short)f2bf(a.z); r[3] = (short)f2bf(a.w);
    r[4] = (short)f2bf(b.x); r[5] = (short)f2bf(b.y);
    r[6] = (short)f2bf(b.z); r[7] = (short)f2bf(b.w);
    return r;
}

// ---------------- Kernel 0: prepack ----------------
// b<4096: mask row -> permuted u8 stream m8p[row][l15][kt][nt] = (e<<2), coalesced via LDS
// [4096,4608): x->bf16 ; [4608,4704): in_w ; [4704,4736): out_w
__global__ __launch_bounds__(256) void pack_kernel(
        const int* __restrict__ mask, const float* __restrict__ x,
        const float* __restrict__ wi, const float* __restrict__ wo,
        unsigned char* __restrict__ m8p, ushort* __restrict__ xb,
        ushort* __restrict__ wib, ushort* __restrict__ wob)
{
    const int b = blockIdx.x;
    const int tid = threadIdx.x;
    if (b < 4096) {
        __shared__ unsigned char rb[4096];
        const int4* src = (const int4*)(mask + (size_t)b * 4096);
#pragma unroll
        for (int i = 0; i < 4; i++) {
            const int j = i * 256 + tid;           // int4 index: ints 4j..4j+3
            int4 v = src[j];
            ((unsigned int*)rb)[j] =
                ((unsigned int)(v.x << 2) & 0xffu)        |
                (((unsigned int)(v.y << 2) & 0xffu) << 8) |
                (((unsigned int)(v.z << 2) & 0xffu) << 16)|
                (((unsigned int)(v.w << 2) & 0xffu) << 24);
        }
        __syncthreads();
        const int l15 = tid >> 4;
        const int kt0 = (tid & 15) * 4;
        unsigned int ow[4];
#pragma unroll
        for (int j4 = 0; j4 < 4; j4++) {
            const int kt = kt0 + j4;
            ow[j4] = (unsigned int)rb[kt * 64 + l15]
                   | ((unsigned int)rb[kt * 64 + 16 + l15] << 8)
                   | ((unsigned int)rb[kt * 64 + 32 + l15] << 16)
                   | ((unsigned int)rb[kt * 64 + 48 + l15] << 24);
        }
        int4 o; o.x = ow[0]; o.y = ow[1]; o.z = ow[2]; o.w = ow[3];
        ((int4*)(m8p + (size_t)b * 4096))[tid] = o;
    } else if (b < 4608) {
        const int t = (b - 4096) * 256 + tid;
        ((bf16x8*)xb)[t] = cvt8(x + t * 8);
    } else if (b < 4704) {
        const int t = (b - 4608) * 256 + tid;
        ((bf16x8*)wib)[t] = cvt8(wi + t * 8);
    } else {
        const int t = (b - 4704) * 256 + tid;
        ((bf16x8*)wob)[t] = cvt8(wo + t * 8);
    }
}

// ---------------- Kernel 1: QKV projection (bf16 in, bf16 Q/K/V^T out) ----------------
__global__ __launch_bounds__(256) void qkv_kernel(
        const ushort* __restrict__ xb, const ushort* __restrict__ wb,
        const float* __restrict__ b,
        ushort* __restrict__ Qb, ushort* __restrict__ Kb, ushort* __restrict__ Vt)
{
    const int lane = threadIdx.x & 63, wv = threadIdx.x >> 6;
    const int quad = lane >> 4, l15 = lane & 15;
    const int m0 = blockIdx.x * 64 + wv * 16;
    const int n0 = blockIdx.y * 64;

    f32x4 acc[4] = {};
    for (int ks = 0; ks < 8; ks++) {
        const int kd = ks * 32 + quad * 8;
        bf16x8 af = *(const bf16x8*)(xb + (m0 + l15) * D + kd);
#pragma unroll
        for (int nt = 0; nt < 4; nt++) {
            bf16x8 bfr = *(const bf16x8*)(wb + (n0 + nt * 16 + l15) * D + kd);
            acc[nt] = __builtin_amdgcn_mfma_f32_16x16x32_bf16(af, bfr, acc[nt], 0, 0, 0);
        }
    }
#pragma unroll
    for (int nt = 0; nt < 4; nt++) {
        const int j = n0 + nt * 16 + l15;
        const float bias = b[j];
#pragma unroll
        for (int r = 0; r < 4; r++) {
            const int row = m0 + quad * 4 + r;
            const float val = acc[nt][r] + bias;
            if (j < 256) {
                Qb[((j >> 5) * L + row) * DH + (j & 31)] = f2bf(val * RS);
            } else if (j < 512) {
                const int jj = j - 256;
                Kb[((jj >> 5) * L + row) * DH + (jj & 31)] = f2bf(val);
            } else {
                const int jj = j - 512;
                Vt[((jj >> 5) * DH + (jj & 31)) * L + row] = f2bf(val);
            }
        }
    }
}

// ---------------- Kernel 2: K-split flash attention, edge bias, no barriers ----------------
// grid (256 q-tiles, SP splits); 8 waves = 8 heads; ktcount = 64/SP iterations per block.
// NOTE: no min-waves clause — forcing occupancy on this register-hot loop caused
// scratch spills in R5 (+168 MB HBM round-trip). Let the allocator breathe.
__global__ __launch_bounds__(512) void attn_kernel(
        const ushort* __restrict__ Qb, const ushort* __restrict__ Kb,
        const ushort* __restrict__ Vt, const unsigned char* __restrict__ m8p,
        const float* __restrict__ edge_bias,
        float* __restrict__ Opart, float* __restrict__ lpart, int ktcount)
{
    __shared__ float ebtab[8 * 16];
    __shared__ __align__(16) ushort Pl[8 * 16 * 72];

    const int tid = threadIdx.x;
    const int lane = tid & 63, h = tid >> 6;
    const int quad = lane >> 4, l15 = lane & 15;
    const int q0 = blockIdx.x * 16;
    const int ktbase = blockIdx.y * ktcount;

    if (lane < 16) {
        ebtab[h * 16 + lane] = (lane < 14)
            ? __builtin_amdgcn_exp2f(edge_bias[lane * H + h] * LOG2E) : 1.0f;
    }
    asm volatile("s_waitcnt lgkmcnt(0)" ::: "memory");   // wave-private table

    const bf16x8 qf = *(const bf16x8*)(Qb + (h * L + q0 + l15) * DH + quad * 8);
    const char* ebh = (const char*)(ebtab + h * 16);
    ushort* Pw = Pl + h * (16 * 72);

    const ushort* Kh  = Kb + h * L * DH;
    const ushort* Vh0 = Vt + (h * DH + l15) * L;
    const ushort* Vh1 = Vt + (h * DH + 16 + l15) * L;

    // single mask base; row r lives at fixed offset r*4096 (fits global-load imm)
    const unsigned char* mbase =
        m8p + ((size_t)(q0 + quad * 4) * 16 + l15) * 256 + ktbase * 4;

    f32x4 o0 = {}, o1 = {};
    float lrow[4] = {0.f, 0.f, 0.f, 0.f};

    for (int kt = 0; kt < ktcount; kt++) {
        const int k0 = (ktbase + kt) * 64;

        // one dword of pre-shifted mask bytes per row (4 regs live, not 16)
        unsigned int mw[4];
#pragma unroll
        for (int r = 0; r < 4; r++)
            mw[r] = *(const unsigned int*)(mbase + r * 4096 + kt * 4);

        // S = (RS*Q) K^T  (16x64), log2 domain
        f32x4 sv[4];
#pragma unroll
        for (int nt = 0; nt < 4; nt++) {
            bf16x8 kf = *(const bf16x8*)(Kh + (k0 + nt * 16 + l15) * DH + quad * 8);
            f32x4 z = {};
            sv[nt] = __builtin_amdgcn_mfma_f32_16x16x32_bf16(qf, kf, z, 0, 0, 0);
        }

        // P = exp2(S) * exp(bias[e]); e<<2 pre-baked in mask bytes
#pragma unroll
        for (int nt = 0; nt < 4; nt++) {
#pragma unroll
            for (int r = 0; r < 4; r++) {
                const int e4 = (mw[r] >> (nt * 8)) & 255;
                const float ebv = *(const float*)(ebh + e4);
                const float p = __builtin_amdgcn_exp2f(sv[nt][r]) * ebv;
                lrow[r] += p;
                union { float f; unsigned int u; } pu; pu.f = p;
                Pw[(quad * 4 + r) * 72 + nt * 16 + l15] = (ushort)((pu.u + 0x8000u) >> 16);
            }
        }
        asm volatile("s_waitcnt lgkmcnt(0)" ::: "memory");   // wave-private RAW fence

        // O += P V
#pragma unroll
        for (int ks2 = 0; ks2 < 2; ks2++) {
            bf16x8 pf = *(const bf16x8*)(Pw + l15 * 72 + ks2 * 32 + quad * 8);
            bf16x8 v0 = *(const bf16x8*)(Vh0 + k0 + ks2 * 32 + quad * 8);
            bf16x8 v1 = *(const bf16x8*)(Vh1 + k0 + ks2 * 32 + quad * 8);
            o0 = __builtin_amdgcn_mfma_f32_16x16x32_bf16(pf, v0, o0, 0, 0, 0);
            o1 = __builtin_amdgcn_mfma_f32_16x16x32_bf16(pf, v1, o1, 0, 0, 0);
        }
    }

    // reduce row-sums across the 16 lanes sharing each q-row
#pragma unroll
    for (int off = 1; off < 16; off <<= 1) {
#pragma unroll
        for (int r = 0; r < 4; r++)
            lrow[r] += __shfl_xor(lrow[r], off, 64);
    }

    float* Op = Opart + (size_t)(blockIdx.y * 8 + h) * L * 32;
#pragma unroll
    for (int r = 0; r < 4; r++) {
        const int row = q0 + quad * 4 + r;
        Op[row * 32 + l15] = o0[r];
        Op[row * 32 + 16 + l15] = o1[r];
    }
    if (l15 == 0) {
#pragma unroll
        for (int r = 0; r < 4; r++)
            lpart[(size_t)(blockIdx.y * 8 + h) * L + q0 + quad * 4 + r] = lrow[r];
    }
}

// ---------------- Kernel 2b: combine split partials -> AO bf16 ----------------
__global__ __launch_bounds__(256) void finalize_kernel(
        const float* __restrict__ Opart, const float* __restrict__ lpart,
        ushort* __restrict__ AO, int SP)
{
    const int t = blockIdx.x * 256 + threadIdx.x;    // t in [0, L*D)
    const int q = t >> 8, c = t & 255;
    const int h = c >> 5, dh = c & 31;
    float o = 0.f, l = 0.f;
    for (int s = 0; s < SP; s++) {
        o += Opart[((size_t)(s * 8 + h) * L + q) * 32 + dh];
        l += lpart[(size_t)(s * 8 + h) * L + q];
    }
    AO[t] = f2bf(o / l);
}

// ---------------- Kernel 3: output projection (bf16 AO, bf16 W -> fp32 out) ----------------
__global__ __launch_bounds__(256) void oproj_kernel(
        const ushort* __restrict__ AO, const ushort* __restrict__ wb,
        const float* __restrict__ b, float* __restrict__ out)
{
    const int lane = threadIdx.x & 63, wv = threadIdx.x >> 6;
    const int quad = lane >> 4, l15 = lane & 15;
    const int m0 = blockIdx.x * 64 + wv * 16;
    const int n0 = blockIdx.y * 64;

    f32x4 acc[4] = {};
    for (int ks = 0; ks < 8; ks++) {
        const int kd = ks * 32 + quad * 8;
        bf16x8 af = *(const bf16x8*)(AO + (m0 + l15) * D + kd);
#pragma unroll
        for (int nt = 0; nt < 4; nt++) {
            bf16x8 bfr = *(const bf16x8*)(wb + (n0 + nt * 16 + l15) * D + kd);
            acc[nt] = __builtin_amdgcn_mfma_f32_16x16x32_bf16(af, bfr, acc[nt], 0, 0, 0);
        }
    }
#pragma unroll
    for (int nt = 0; nt < 4; nt++) {
        const int j = n0 + nt * 16 + l15;
        const float bias = b[j];
#pragma unroll
        for (int r = 0; r < 4; r++) {
            const int row = m0 + quad * 4 + r;
            out[row * D + j] = acc[nt][r] + bias;
        }
    }
}

extern "C" void kernel_launch(void* const* d_in, const int* in_sizes, int n_in,
                              void* d_out, int out_size, void* d_ws, size_t ws_size,
                              hipStream_t stream) {
    const float* x     = (const float*)d_in[0];
    const int*   mask  = (const int*)d_in[1];
    const float* in_w  = (const float*)d_in[2];
    const float* in_b  = (const float*)d_in[3];
    const float* out_w = (const float*)d_in[4];
    const float* out_b = (const float*)d_in[5];
    const float* eb    = (const float*)d_in[6];

    ushort* ws = (ushort*)d_ws;
    ushort* Qb  = ws;                          // 1M elems each
    ushort* Kb  = Qb + H * L * DH;
    ushort* Vt  = Kb + H * L * DH;
    ushort* xb  = Vt + H * L * DH;             // x bf16; reused as AO after attn
    ushort* wib = xb + L * D;
    ushort* wob = wib + 3 * D * D;
    unsigned char* m8p = (unsigned char*)(wob + D * D);          // 16 MB
    float* Opart = (float*)(m8p + (size_t)L * L);
    // fixed part = 25,690,112 B; per split: Opart 4,194,304 + lpart 131,072 B
    int SP = (ws_size >= (size_t)25690112 + 4u * 4325376u) ? 4
           : (ws_size >= (size_t)25690112 + 2u * 4325376u) ? 2 : 1;
    float* lpart = Opart + (size_t)SP * H * L * DH;
    ushort* AO = xb;
    float* out = (float*)d_out;

    pack_kernel<<<dim3(4736), 256, 0, stream>>>(mask, x, in_w, out_w, m8p, xb, wib, wob);
    qkv_kernel<<<dim3(64, 12), 256, 0, stream>>>(xb, wib, in_b, Qb, Kb, Vt);
    attn_kernel<<<dim3(256, SP), 512, 0, stream>>>(Qb, Kb, Vt, m8p, eb, Opart, lpart, 64 / SP);
    finalize_kernel<<<dim3(4096), 256, 0, stream>>>(Opart, lpart, AO, SP);
    oproj_kernel<<<dim3(64, 4), 256, 0, stream>>>(AO, wob, out_b, out);
}

// Round 7
// 229.708 us; speedup vs baseline: 1.4054x; 1.2941x over previous
//
#include <hip/hip_runtime.h>
#include <hip/hip_bf16.h>

#define L 4096
#define D 256
#define H 8
#define DH 32

typedef __attribute__((ext_vector_type(8))) short bf16x8;
typedef __attribute__((ext_vector_type(4))) float f32x4;

#define LOG2E 1.4426950408889634f
#define RS (0.17677669529663688f * LOG2E)   // 1/sqrt(DH) * log2(e), folded into Q

__device__ __forceinline__ ushort f2bf(float f) {
    union { float f; unsigned int i; } v; v.f = f;
    unsigned int x = v.i;
    return (ushort)((x + 0x7fffu + ((x >> 16) & 1u)) >> 16);   // RNE
}
__device__ __forceinline__ bf16x8 cvt8(const float* p) {
    float4 a = *(const float4*)p;
    float4 b = *(const float4*)(p + 4);
    bf16x8 r;
    r[0] = (short)f2bf(a.x); r[1] = (short)f2bf(a.y);
    r[2] = (short)f2bf(a.z); r[3] = (short)f2bf(a.w);
    r[4] = (short)f2bf(b.x); r[5] = (short)f2bf(b.y);
    r[6] = (short)f2bf(b.z); r[7] = (short)f2bf(b.w);
    return r;
}

// sigma: logical key u (0..63) -> K storage row within its 64-block.
// chosen so S^T lane (quad qd) regs hold exactly PV B-frag's k = 32w+8qd+4t+r
__device__ __forceinline__ int ksig(int u) {
    return 32 * (u >> 5) + 16 * ((u >> 2) & 1) + 4 * ((u >> 3) & 3) + (u & 3);
}

// ---------------- Kernel 0: prepack ----------------
// b<512: mask rows 8b..8b+8 -> sigma-permuted e<<4 byte stream
//        m2 dword[t][kt][lane][nt], t=q-tile, lane=(qd*16+l15)
// [512,1024): x->bf16 ; [1024,1120): in_w ; [1120,1152): out_w
__global__ __launch_bounds__(256) void pack_kernel(
        const int* __restrict__ mask, const float* __restrict__ x,
        const float* __restrict__ wi, const float* __restrict__ wo,
        unsigned int* __restrict__ m2, ushort* __restrict__ xb,
        ushort* __restrict__ wib, ushort* __restrict__ wob)
{
    const int b = blockIdx.x;
    const int tid = threadIdx.x;
    if (b < 512) {
        __shared__ unsigned int rb[8 * 1025];   // 8 rows x 4096 bytes, +4B pad per row
        const int4* src = (const int4*)(mask + (size_t)b * 8 * 4096);
#pragma unroll
        for (int i = 0; i < 32; i++) {
            const int g = i * 256 + tid;        // int4 index; row=g>>10, dword-col=g&1023
            int4 v = src[g];
            rb[(g >> 10) * 1025 + (g & 1023)] =
                ((unsigned int)(v.x & 15) << 4)  | ((unsigned int)(v.y & 15) << 12) |
                ((unsigned int)(v.z & 15) << 20) | ((unsigned int)(v.w & 15) << 28);
        }
        __syncthreads();
        const int t = b >> 1, half = b & 1;
#pragma unroll
        for (int i = 0; i < 32; i++) {
            const int dd = i * 256 + tid;       // 8192 output dwords for this half-tile
            const int nt = dd & 3, s = (dd >> 2) & 7, qd = (dd >> 5) & 3, kt = dd >> 7;
            const unsigned int w =
                rb[s * 1025 + kt * 16 + 8 * (nt >> 1) + 2 * qd + (nt & 1)];
            m2[(size_t)t * 16384 + kt * 256 + (qd * 16 + 8 * half + s) * 4 + nt] = w;
        }
    } else if (b < 1024) {
        const int t = (b - 512) * 256 + tid;
        ((bf16x8*)xb)[t] = cvt8(x + t * 8);
    } else if (b < 1120) {
        const int t = (b - 1024) * 256 + tid;
        ((bf16x8*)wib)[t] = cvt8(wi + t * 8);
    } else {
        const int t = (b - 1120) * 256 + tid;
        ((bf16x8*)wob)[t] = cvt8(wo + t * 8);
    }
}

// ---------------- Kernel 1: QKV projection (bf16 in, bf16 Q/K(sigma)/V^T out) ----------------
__global__ __launch_bounds__(256) void qkv_kernel(
        const ushort* __restrict__ xb, const ushort* __restrict__ wb,
        const float* __restrict__ b,
        ushort* __restrict__ Qb, ushort* __restrict__ Kb, ushort* __restrict__ Vt)
{
    const int lane = threadIdx.x & 63, wv = threadIdx.x >> 6;
    const int quad = lane >> 4, l15 = lane & 15;
    const int m0 = blockIdx.x * 64 + wv * 16;
    const int n0 = blockIdx.y * 64;

    f32x4 acc[4] = {};
    for (int ks = 0; ks < 8; ks++) {
        const int kd = ks * 32 + quad * 8;
        bf16x8 af = *(const bf16x8*)(xb + (m0 + l15) * D + kd);
#pragma unroll
        for (int nt = 0; nt < 4; nt++) {
            bf16x8 bfr = *(const bf16x8*)(wb + (n0 + nt * 16 + l15) * D + kd);
            acc[nt] = __builtin_amdgcn_mfma_f32_16x16x32_bf16(af, bfr, acc[nt], 0, 0, 0);
        }
    }
#pragma unroll
    for (int nt = 0; nt < 4; nt++) {
        const int j = n0 + nt * 16 + l15;
        const float bias = b[j];
#pragma unroll
        for (int r = 0; r < 4; r++) {
            const int row = m0 + quad * 4 + r;
            const float val = acc[nt][r] + bias;
            if (j < 256) {
                Qb[((j >> 5) * L + row) * DH + (j & 31)] = f2bf(val * RS);
            } else if (j < 512) {
                const int jj = j - 256;
                const int srow = (row & ~63) + ksig(row & 63);   // sigma permute
                Kb[((jj >> 5) * L + srow) * DH + (jj & 31)] = f2bf(val);
            } else {
                const int jj = j - 512;
                Vt[((jj >> 5) * DH + (jj & 31)) * L + row] = f2bf(val);
            }
        }
    }
}

// ---------------- Kernel 2: register-resident flash attention ----------------
// S^T = K(sigma) Q^T so P stays in registers (no LDS round-trip, no fences).
// 512 thr = 8 waves = 8 heads; 16 q-rows/block; K-split over blockIdx.y.
__global__ __launch_bounds__(512) void attn_kernel(
        const ushort* __restrict__ Qb, const ushort* __restrict__ Kb,
        const ushort* __restrict__ Vt, const unsigned char* __restrict__ m2,
        const float* __restrict__ edge_bias,
        float* __restrict__ Opart, float* __restrict__ lpart, int ktcount)
{
    __shared__ float ebt[8 * 64];   // [h][e(16)][copy(4)] fp32 = bias*log2e, x4 bank-replicated

    const int tid = threadIdx.x;
    const int lane = tid & 63, h = tid >> 6;
    const int quad = lane >> 4, l15 = lane & 15;
    const int q0 = blockIdx.x * 16;
    const int ktbase = blockIdx.y * ktcount;

    {   // wave-private table init: lane = e*4+c for head h
        const int c = lane & 3, e = (lane >> 2) & 15;
        ebt[h * 64 + e * 4 + c] = (e < 14) ? edge_bias[e * H + h] * LOG2E : 0.f;
    }
    asm volatile("s_waitcnt lgkmcnt(0)" ::: "memory");   // one-time, outside the loop

    const bf16x8 qf = *(const bf16x8*)(Qb + (h * L + q0 + l15) * DH + quad * 8);
    const char* ebp = (const char*)ebt + h * 256 + (l15 & 3) * 4;   // e<<4 indexes directly

    const ushort* Kh  = Kb + h * L * DH;
    const ushort* Vh0 = Vt + (h * DH + l15) * L;
    const ushort* Vh1 = Vt + (h * DH + 16 + l15) * L;
    const unsigned char* mrow = m2 + (size_t)blockIdx.x * 65536 + lane * 16;

    f32x4 o0 = {}, o1 = {};
    float lrow = 0.f;

    for (int kt = 0; kt < ktcount; kt++) {
        const int ktg = ktbase + kt;
        const int k0 = ktg * 64;

        const int4 mw4 = *(const int4*)(mrow + (size_t)ktg * 1024);
        unsigned int mwa[4] = {(unsigned int)mw4.x, (unsigned int)mw4.y,
                               (unsigned int)mw4.z, (unsigned int)mw4.w};

        // S^T = K(sigma-rows) Q^T : lane holds scores for q=l15, k=sigma^-1(row)
        f32x4 sv[4];
#pragma unroll
        for (int nt = 0; nt < 4; nt++) {
            bf16x8 kf = *(const bf16x8*)(Kh + (k0 + nt * 16 + l15) * DH + quad * 8);
            f32x4 z = {};
            sv[nt] = __builtin_amdgcn_mfma_f32_16x16x32_bf16(kf, qf, z, 0, 0, 0);
        }

        // P^T = exp2(S^T + b2[e]) — pure register math, byte e<<4 pre-baked in mask stream
        unsigned int pu[4][4];
#pragma unroll
        for (int nt = 0; nt < 4; nt++) {
#pragma unroll
            for (int r = 0; r < 4; r++) {
                const int off = (mwa[nt] >> (r * 8)) & 255;
                const float b2 = *(const float*)(ebp + off);
                const float p = __builtin_amdgcn_exp2f(sv[nt][r] + b2);
                lrow += p;
                union { float f; unsigned int u; } c; c.f = p;
                pu[nt][r] = c.u;
            }
        }

        // pack fp32 pairs -> bf16x2 dwords (round-half-up); assemble PV B-fragments
        union { bf16x8 v; unsigned int u[4]; } pf0, pf1;
#pragma unroll
        for (int nt = 0; nt < 4; nt++) {
            const unsigned int d0 = (((pu[nt][1] + 0x8000u) & 0xffff0000u)) |
                                    ((pu[nt][0] + 0x8000u) >> 16);
            const unsigned int d1 = (((pu[nt][3] + 0x8000u) & 0xffff0000u)) |
                                    ((pu[nt][2] + 0x8000u) >> 16);
            if (nt < 2) { pf0.u[nt * 2] = d0; pf0.u[nt * 2 + 1] = d1; }
            else        { pf1.u[(nt - 2) * 2] = d0; pf1.u[(nt - 2) * 2 + 1] = d1; }
        }

        // O^T += V^T P^T  (V plain logical layout; windows w=0,1 of 32 keys)
        bf16x8 v00 = *(const bf16x8*)(Vh0 + k0 + quad * 8);
        bf16x8 v01 = *(const bf16x8*)(Vh1 + k0 + quad * 8);
        bf16x8 v10 = *(const bf16x8*)(Vh0 + k0 + 32 + quad * 8);
        bf16x8 v11 = *(const bf16x8*)(Vh1 + k0 + 32 + quad * 8);
        o0 = __builtin_amdgcn_mfma_f32_16x16x32_bf16(v00, pf0.v, o0, 0, 0, 0);
        o1 = __builtin_amdgcn_mfma_f32_16x16x32_bf16(v01, pf0.v, o1, 0, 0, 0);
        o0 = __builtin_amdgcn_mfma_f32_16x16x32_bf16(v10, pf1.v, o0, 0, 0, 0);
        o1 = __builtin_amdgcn_mfma_f32_16x16x32_bf16(v11, pf1.v, o1, 0, 0, 0);
    }

    // row-sum: lane already has all its keys for q=l15; reduce across the 4 quads
    lrow += __shfl_xor(lrow, 16, 64);
    lrow += __shfl_xor(lrow, 32, 64);

    // O^T C-layout: q=l15 (col), d=quad*4+reg (row) -> [q][d] fp32 partials
    float* Op = Opart + (size_t)(blockIdx.y * 8 + h) * L * 32 + (q0 + l15) * 32;
    float4 s0 = {o0[0], o0[1], o0[2], o0[3]};
    float4 s1 = {o1[0], o1[1], o1[2], o1[3]};
    *(float4*)(Op + quad * 4) = s0;
    *(float4*)(Op + 16 + quad * 4) = s1;
    if (quad == 0)
        lpart[(size_t)(blockIdx.y * 8 + h) * L + q0 + l15] = lrow;
}

// ---------------- Kernel 2b: combine split partials -> AO bf16 ----------------
__global__ __launch_bounds__(256) void finalize_kernel(
        const float* __restrict__ Opart, const float* __restrict__ lpart,
        ushort* __restrict__ AO, int SP)
{
    const int t = blockIdx.x * 256 + threadIdx.x;    // t in [0, L*D)
    const int q = t >> 8, c = t & 255;
    const int h = c >> 5, dh = c & 31;
    float o = 0.f, l = 0.f;
    for (int s = 0; s < SP; s++) {
        o += Opart[((size_t)(s * 8 + h) * L + q) * 32 + dh];
        l += lpart[(size_t)(s * 8 + h) * L + q];
    }
    AO[t] = f2bf(o / l);
}

// ---------------- Kernel 3: output projection (bf16 AO, bf16 W -> fp32 out) ----------------
__global__ __launch_bounds__(256) void oproj_kernel(
        const ushort* __restrict__ AO, const ushort* __restrict__ wb,
        const float* __restrict__ b, float* __restrict__ out)
{
    const int lane = threadIdx.x & 63, wv = threadIdx.x >> 6;
    const int quad = lane >> 4, l15 = lane & 15;
    const int m0 = blockIdx.x * 64 + wv * 16;
    const int n0 = blockIdx.y * 64;

    f32x4 acc[4] = {};
    for (int ks = 0; ks < 8; ks++) {
        const int kd = ks * 32 + quad * 8;
        bf16x8 af = *(const bf16x8*)(AO + (m0 + l15) * D + kd);
#pragma unroll
        for (int nt = 0; nt < 4; nt++) {
            bf16x8 bfr = *(const bf16x8*)(wb + (n0 + nt * 16 + l15) * D + kd);
            acc[nt] = __builtin_amdgcn_mfma_f32_16x16x32_bf16(af, bfr, acc[nt], 0, 0, 0);
        }
    }
#pragma unroll
    for (int nt = 0; nt < 4; nt++) {
        const int j = n0 + nt * 16 + l15;
        const float bias = b[j];
#pragma unroll
        for (int r = 0; r < 4; r++) {
            const int row = m0 + quad * 4 + r;
            out[row * D + j] = acc[nt][r] + bias;
        }
    }
}

extern "C" void kernel_launch(void* const* d_in, const int* in_sizes, int n_in,
                              void* d_out, int out_size, void* d_ws, size_t ws_size,
                              hipStream_t stream) {
    const float* x     = (const float*)d_in[0];
    const int*   mask  = (const int*)d_in[1];
    const float* in_w  = (const float*)d_in[2];
    const float* in_b  = (const float*)d_in[3];
    const float* out_w = (const float*)d_in[4];
    const float* out_b = (const float*)d_in[5];
    const float* eb    = (const float*)d_in[6];

    ushort* ws = (ushort*)d_ws;
    ushort* Qb  = ws;                          // 1M elems each
    ushort* Kb  = Qb + H * L * DH;             // sigma-permuted rows
    ushort* Vt  = Kb + H * L * DH;
    ushort* xb  = Vt + H * L * DH;             // x bf16; reused as AO after attn
    ushort* wib = xb + L * D;
    ushort* wob = wib + 3 * D * D;
    unsigned char* m2 = (unsigned char*)(wob + D * D);           // 16 MB e<<4 stream
    float* Opart = (float*)(m2 + (size_t)L * L);
    // fixed part = 25,690,112 B; per split: Opart 4,194,304 + lpart 131,072 B
    int SP = (ws_size >= (size_t)25690112 + 4u * 4325376u) ? 4
           : (ws_size >= (size_t)25690112 + 2u * 4325376u) ? 2 : 1;
    float* lpart = Opart + (size_t)SP * H * L * DH;
    ushort* AO = xb;
    float* out = (float*)d_out;

    pack_kernel<<<dim3(1152), 256, 0, stream>>>(mask, x, in_w, out_w,
                                                (unsigned int*)m2, xb, wib, wob);
    qkv_kernel<<<dim3(64, 12), 256, 0, stream>>>(xb, wib, in_b, Qb, Kb, Vt);
    attn_kernel<<<dim3(256, SP), 512, 0, stream>>>(Qb, Kb, Vt, m2, eb, Opart, lpart, 64 / SP);
    finalize_kernel<<<dim3(4096), 256, 0, stream>>>(Opart, lpart, AO, SP);
    oproj_kernel<<<dim3(64, 4), 256, 0, stream>>>(AO, wob, out_b, out);
}